// Round 6
// baseline (462.463 us; speedup 1.0000x reference)
//
#include <hip/hip_runtime.h>

#define TPB 256
#define GRID1 1024
#define GRID2 2048

typedef __attribute__((ext_vector_type(8))) short short8;
typedef __attribute__((ext_vector_type(4))) float floatx4;

__device__ __forceinline__ unsigned short bf_rne(float f){
    union { float f; unsigned u; } c; c.f = f;
    unsigned r = c.u + 0x7fffu + ((c.u >> 16) & 1u);
    return (unsigned short)(r >> 16);
}
// pack trunc-bf16 of (lo,hi) into one dword with a single v_perm_b32
__device__ __forceinline__ unsigned pack_bf(float lo, float hi){
    union { float f; unsigned u; } a, b; a.f = lo; b.f = hi;
    return __builtin_amdgcn_perm(b.u, a.u, 0x07060302u);
}
// f32 -> f16 bits (RNE via v_cvt_f16_f32; no amdgcn builtin needed)
__device__ __forceinline__ unsigned short f2h(float a){
    union { _Float16 f; unsigned short u; } c; c.f = (_Float16)a; return c.u;
}
__device__ __forceinline__ unsigned pk16(float a, float b){
    return (unsigned)f2h(a) | ((unsigned)f2h(b) << 16);
}
__device__ __forceinline__ float h2f(unsigned short u){
    union { unsigned short u; _Float16 f; } c; c.u = u; return (float)c.f;
}

// ---------------------------------------------------------------------------
// prologue: batch boundaries lb[0..B] once.
// ---------------------------------------------------------------------------
__global__ void lb_kernel(const int* __restrict__ bidx, int* __restrict__ ws_lb,
                          int N, int B)
{
    const int t = threadIdx.x;
    if (t <= B){
        int lo = 0, hi = N;
        while (lo < hi){
            const int mid = (lo + hi) >> 1;
            if (bidx[mid] < t) lo = mid + 1; else hi = mid;
        }
        ws_lb[t] = lo;
    }
}

// ---------------------------------------------------------------------------
// R6 pass1 = R3 structure (verified bit-exact: coalesced loads + wave-private
// swizzled LDS bounce, no barriers) PLUS: stores h = feats@W1 + b1 as packed
// f16 to workspace (128 MB). Removes the MFMA + feats re-read from pass2.
// (R5 intent; rebuilt without __builtin_amdgcn_cvt_pkrtz / occupancy API,
// which broke the R5 compile.)
// ---------------------------------------------------------------------------
__global__ __launch_bounds__(TPB) void pass1_kernel(
    const float* __restrict__ feats, const int* __restrict__ ws_lb,
    const float* __restrict__ w1, const float* __restrict__ b1,
    const float* __restrict__ mw1, const float* __restrict__ mb1,
    const float* __restrict__ mw2, const float* __restrict__ mb2,
    float* __restrict__ mask_out, unsigned short* __restrict__ h_out,
    float* __restrict__ ws_sum, float* __restrict__ ws_sq,
    float* __restrict__ ws_pool, int N, int B)
{
    __shared__ float s_stage[TPB/64][1024];   // 4KB per wave
    __shared__ float s_pool[8][32];
    __shared__ float s_sum[32];
    __shared__ float s_sq[32];
    __shared__ int   s_lb[9];

    const int tid  = threadIdx.x;
    const int lane = tid & 63;
    const int wv   = tid >> 6;
    const int p = lane & 15;               // MFMA point col
    const int q = lane >> 4;               // k-group

    if (tid < 32){ s_sum[tid] = 0.f; s_sq[tid] = 0.f; }
    ((float*)s_pool)[tid] = 0.f;
    if (tid <= B) s_lb[tid] = ws_lb[tid];
    __syncthreads();

    short8 aw0, aw1, am0, am1;
    floatx4 ci_h0, ci_h1, ci_m0, ci_m1;
    float mw2v[8];
#pragma unroll
    for (int j = 0; j < 8; ++j){
        const int k = q * 8 + j;
        aw0[j] = (short)bf_rne(w1 [k * 32 + p]);
        aw1[j] = (short)bf_rne(w1 [k * 32 + 16 + p]);
        am0[j] = (short)bf_rne(mw1[k * 32 + p]);
        am1[j] = (short)bf_rne(mw1[k * 32 + 16 + p]);
    }
#pragma unroll
    for (int r = 0; r < 4; ++r){
        const int c0 = q * 4 + r, c1 = 16 + q * 4 + r;
        ci_h0[r] = b1[c0];  ci_h1[r] = b1[c1];
        ci_m0[r] = mb1[c0]; ci_m1[r] = mb1[c1];
        mw2v[r] = mw2[c0];  mw2v[4 + r] = mw2[c1];
    }
    const float mb2s = mb2[0];

    float hsum[8] = {0,0,0,0,0,0,0,0};
    float hsq [8] = {0,0,0,0,0,0,0,0};
    float pacc[4] = {0,0,0,0};

    const int ngroups = (N + 31) >> 5;                   // 32-row groups
    const int nw  = gridDim.x * (TPB / 64);
    const int wid = blockIdx.x * (TPB / 64) + wv;
    const int g0  = (int)((long)wid       * ngroups / nw);
    const int gE  = (int)((long)(wid + 1) * ngroups / nw);

    int curb = 0;
    { const int r = g0 << 5; while (curb < B - 1 && r >= s_lb[curb + 1]) curb++; }
    int lbn = s_lb[curb + 1];

    float* sw = &s_stage[wv][0];
    const int wrow  = lane >> 3;                 // staging row-in-chunk 0..7
    const int wg    = (lane & 7) ^ wrow;         // swizzled write granule
    const int cbase = (lane & 7) << 2;           // pooled channel base
    const int wo0 = ( 0 + wrow) * 32 + (wg << 2);
    const int wo1 = ( 8 + wrow) * 32 + (wg << 2);
    const int wo2 = (16 + wrow) * 32 + (wg << 2);
    const int wo3 = (24 + wrow) * 32 + (wg << 2);
    const int e = p & 7;
    const int ra0 = p * 32        + ((((q << 1)    ) ^ e) << 2);
    const int ra1 = p * 32        + ((((q << 1) + 1) ^ e) << 2);
    const int rb0 = (16 + p) * 32 + ((((q << 1)    ) ^ e) << 2);
    const int rb1 = (16 + p) * 32 + ((((q << 1) + 1) ^ e) << 2);

    // prime group g0
    floatx4 sv0 = {0,0,0,0}, sv1 = {0,0,0,0}, sv2 = {0,0,0,0}, sv3 = {0,0,0,0};
    if (g0 < gE){
        const float* gp = feats + ((size_t)g0 << 10) + (lane << 2);
        const int r = (g0 << 5) + wrow;
        if (r + 24 < N){
            sv0 = *(const floatx4*)(gp);
            sv1 = *(const floatx4*)(gp + 256);
            sv2 = *(const floatx4*)(gp + 512);
            sv3 = *(const floatx4*)(gp + 768);
        } else {
            if (r      < N) sv0 = *(const floatx4*)(gp);
            if (r +  8 < N) sv1 = *(const floatx4*)(gp + 256);
            if (r + 16 < N) sv2 = *(const floatx4*)(gp + 512);
            if (r + 24 < N) sv3 = *(const floatx4*)(gp + 768);
        }
    }

    for (int g = g0; g < gE; ++g){
        // 1. stage current group into wave-private LDS (swizzled, b128)
        *(floatx4*)(sw + wo0) = sv0;
        *(floatx4*)(sw + wo1) = sv1;
        *(floatx4*)(sw + wo2) = sv2;
        *(floatx4*)(sw + wo3) = sv3;

        // 2. prefetch next group (coalesced 1KB/instruction)
        floatx4 nv0 = {0,0,0,0}, nv1 = {0,0,0,0}, nv2 = {0,0,0,0}, nv3 = {0,0,0,0};
        if (g + 1 < gE){
            const float* gp = feats + ((size_t)(g + 1) << 10) + (lane << 2);
            const int r = ((g + 1) << 5) + wrow;
            if (r + 24 < N){
                nv0 = *(const floatx4*)(gp);
                nv1 = *(const floatx4*)(gp + 256);
                nv2 = *(const floatx4*)(gp + 512);
                nv3 = *(const floatx4*)(gp + 768);
            } else {
                if (r      < N) nv0 = *(const floatx4*)(gp);
                if (r +  8 < N) nv1 = *(const floatx4*)(gp + 256);
                if (r + 16 < N) nv2 = *(const floatx4*)(gp + 512);
                if (r + 24 < N) nv3 = *(const floatx4*)(gp + 768);
            }
        }

        // 3. pooled accumulation from staged registers
        const int r0 = g << 5;
        if (r0 >= lbn){
#pragma unroll
            for (int j = 0; j < 4; ++j){
                if (pacc[j] != 0.f) atomicAdd(&s_pool[curb][cbase + j], pacc[j]);
                pacc[j] = 0.f;
            }
            do { curb++; } while (curb < B - 1 && r0 >= s_lb[curb + 1]);
            lbn = s_lb[curb + 1];
        }
        const bool slow = (r0 + 31 >= lbn) || (r0 + 31 >= N);

        if (!slow){
            pacc[0] += sv0[0] + sv1[0] + sv2[0] + sv3[0];
            pacc[1] += sv0[1] + sv1[1] + sv2[1] + sv3[1];
            pacc[2] += sv0[2] + sv1[2] + sv2[2] + sv3[2];
            pacc[3] += sv0[3] + sv1[3] + sv2[3] + sv3[3];
        } else {
#define SLOWROW(SV, L) { \
            const int row = r0 + (L * 8) + wrow; \
            if (row < N){ \
                int bl = curb; \
                for (int c = curb + 1; c < B; ++c) bl += (row >= s_lb[c]); \
                atomicAdd(&s_pool[bl][cbase + 0], SV[0]); \
                atomicAdd(&s_pool[bl][cbase + 1], SV[1]); \
                atomicAdd(&s_pool[bl][cbase + 2], SV[2]); \
                atomicAdd(&s_pool[bl][cbase + 3], SV[3]); \
            } }
            SLOWROW(sv0, 0) SLOWROW(sv1, 1) SLOWROW(sv2, 2) SLOWROW(sv3, 3)
#undef SLOWROW
        }

        // 4. MFMA fragments back from LDS (swizzled read, bank-uniform)
        const floatx4 vA0 = *(const floatx4*)(sw + ra0);
        const floatx4 vA1 = *(const floatx4*)(sw + ra1);
        const floatx4 vB0 = *(const floatx4*)(sw + rb0);
        const floatx4 vB1 = *(const floatx4*)(sw + rb1);

        short8 bfA, bfB;
        {
            unsigned* ba = (unsigned*)&bfA;
            ba[0] = pack_bf(vA0[0], vA0[1]); ba[1] = pack_bf(vA0[2], vA0[3]);
            ba[2] = pack_bf(vA1[0], vA1[1]); ba[3] = pack_bf(vA1[2], vA1[3]);
            unsigned* bb = (unsigned*)&bfB;
            bb[0] = pack_bf(vB0[0], vB0[1]); bb[1] = pack_bf(vB0[2], vB0[3]);
            bb[2] = pack_bf(vB1[0], vB1[1]); bb[3] = pack_bf(vB1[2], vB1[3]);
        }

        const floatx4 chA0 = __builtin_amdgcn_mfma_f32_16x16x32_bf16(aw0, bfA, ci_h0, 0, 0, 0);
        const floatx4 chA1 = __builtin_amdgcn_mfma_f32_16x16x32_bf16(aw1, bfA, ci_h1, 0, 0, 0);
        const floatx4 cmA0 = __builtin_amdgcn_mfma_f32_16x16x32_bf16(am0, bfA, ci_m0, 0, 0, 0);
        const floatx4 cmA1 = __builtin_amdgcn_mfma_f32_16x16x32_bf16(am1, bfA, ci_m1, 0, 0, 0);
        const floatx4 chB0 = __builtin_amdgcn_mfma_f32_16x16x32_bf16(aw0, bfB, ci_h0, 0, 0, 0);
        const floatx4 chB1 = __builtin_amdgcn_mfma_f32_16x16x32_bf16(aw1, bfB, ci_h1, 0, 0, 0);
        const floatx4 cmB0 = __builtin_amdgcn_mfma_f32_16x16x32_bf16(am0, bfB, ci_m0, 0, 0, 0);
        const floatx4 cmB1 = __builtin_amdgcn_mfma_f32_16x16x32_bf16(am1, bfB, ci_m1, 0, 0, 0);

        // 5. h f16 store (rows rA/rB; channels q*4..q*4+3 and 16+q*4..)
        {
            const int rA = r0 + p, rB = r0 + 16 + p;
            if (rA < N){
                uint2 wlo, whi;
                wlo.x = pk16(chA0[0], chA0[1]); wlo.y = pk16(chA0[2], chA0[3]);
                whi.x = pk16(chA1[0], chA1[1]); whi.y = pk16(chA1[2], chA1[3]);
                *(uint2*)(h_out + (size_t)rA * 32 + q * 4)      = wlo;
                *(uint2*)(h_out + (size_t)rA * 32 + 16 + q * 4) = whi;
            }
            if (rB < N){
                uint2 wlo, whi;
                wlo.x = pk16(chB0[0], chB0[1]); wlo.y = pk16(chB0[2], chB0[3]);
                whi.x = pk16(chB1[0], chB1[1]); whi.y = pk16(chB1[2], chB1[3]);
                *(uint2*)(h_out + (size_t)rB * 32 + q * 4)      = wlo;
                *(uint2*)(h_out + (size_t)rB * 32 + 16 + q * 4) = whi;
            }
        }

        if (r0 + 31 < N){
#pragma unroll
            for (int r = 0; r < 4; ++r){
                const float a0 = chA0[r], b0 = chB0[r];
                hsum[r] += a0 + b0;
                hsq [r] = fmaf(a0, a0, fmaf(b0, b0, hsq[r]));
                const float a1 = chA1[r], b1v = chB1[r];
                hsum[4 + r] += a1 + b1v;
                hsq [4 + r] = fmaf(a1, a1, fmaf(b1v, b1v, hsq[4 + r]));
            }
        } else {
            if (r0 + p < N){
#pragma unroll
                for (int r = 0; r < 4; ++r){
                    const float a0 = chA0[r]; hsum[r]     += a0; hsq[r]     = fmaf(a0, a0, hsq[r]);
                    const float a1 = chA1[r]; hsum[4 + r] += a1; hsq[4 + r] = fmaf(a1, a1, hsq[4 + r]);
                }
            }
            if (r0 + 16 + p < N){
#pragma unroll
                for (int r = 0; r < 4; ++r){
                    const float b0 = chB0[r]; hsum[r]     += b0; hsq[r]     = fmaf(b0, b0, hsq[r]);
                    const float b1v = chB1[r]; hsum[4 + r] += b1v; hsq[4 + r] = fmaf(b1v, b1v, hsq[4 + r]);
                }
            }
        }

        float tmA = 0.f, tmB = 0.f;
#pragma unroll
        for (int r = 0; r < 4; ++r){
            tmA = fmaf(fmaxf(cmA0[r], 0.f), mw2v[r],     tmA);
            tmA = fmaf(fmaxf(cmA1[r], 0.f), mw2v[4 + r], tmA);
            tmB = fmaf(fmaxf(cmB0[r], 0.f), mw2v[r],     tmB);
            tmB = fmaf(fmaxf(cmB1[r], 0.f), mw2v[4 + r], tmB);
        }
        tmA += __shfl_xor(tmA, 16, 64); tmA += __shfl_xor(tmA, 32, 64);
        tmB += __shfl_xor(tmB, 16, 64); tmB += __shfl_xor(tmB, 32, 64);
        if (q == 0 && (r0 + p) < N)      mask_out[r0 + p]      = tmA + mb2s;
        if (q == 0 && (r0 + 16 + p) < N) mask_out[r0 + 16 + p] = tmB + mb2s;

        sv0 = nv0; sv1 = nv1; sv2 = nv2; sv3 = nv3;
    }

    // final flush
#pragma unroll
    for (int j = 0; j < 4; ++j){
        if (pacc[j] != 0.f) atomicAdd(&s_pool[curb][cbase + j], pacc[j]);
    }
#pragma unroll
    for (int i = 0; i < 8; ++i){
        const int ch = (i >> 2) * 16 + q * 4 + (i & 3);
        atomicAdd(&s_sum[ch], hsum[i]);
        atomicAdd(&s_sq[ch],  hsq[i]);
    }
    __syncthreads();
    if (tid < 32){
        atomicAdd(&ws_sum[tid], s_sum[tid]);
        atomicAdd(&ws_sq[tid],  s_sq[tid]);
    }
    {
        const float pv = ((float*)s_pool)[tid];
        if (pv != 0.f) atomicAdd(&ws_pool[tid], pv);
    }
}

// ---------------------------------------------------------------------------
// R6 pass2: PURE STREAM. Reads h.f16 (128 MB, lane-contiguous 1KB/wave,
// L3-hot from pass1), applies BN fold + relu + 32->3 quad dot (2 shfl_xor
// per output), writes pt. No MFMA / LDS staging / atomics. This kernel IS
// the ablation: its duration measures the harness streaming-read rate.
// Block 0 also writes pooled + iou from ws.
// ---------------------------------------------------------------------------
__global__ __launch_bounds__(TPB) void pass2_kernel(
    const unsigned short* __restrict__ h_in, const int* __restrict__ ws_lb,
    const float* __restrict__ gamma, const float* __restrict__ beta,
    const float* __restrict__ w2, const float* __restrict__ b2,
    const float* __restrict__ iw, const float* __restrict__ ib,
    const float* __restrict__ ws_sum, const float* __restrict__ ws_sq,
    const float* __restrict__ ws_pool,
    float* __restrict__ pt_out, float* __restrict__ pooled_out,
    float* __restrict__ iou_out, int N, int B)
{
    __shared__ float s_sc[32];
    __shared__ float s_bp[32];
    __shared__ float s_pooled[256];
    __shared__ int   s_lb[9];

    const int tid = threadIdx.x;

    if (tid < 32){
        const float invN = 1.f / (float)N;
        const float mu  = ws_sum[tid] * invN;
        const float var = ws_sq[tid] * invN - mu * mu;
        const float s   = gamma[tid] * rsqrtf(var + 1e-4f);
        s_sc[tid] = s;
        s_bp[tid] = beta[tid] - mu * s;        // h already includes b1
    }
    if (tid <= B) s_lb[tid] = ws_lb[tid];
    __syncthreads();

    if (blockIdx.x == 0){
        if (tid < B * 32){
            const int bb = tid >> 5;
            const float cnt = fmaxf((float)(s_lb[bb + 1] - s_lb[bb]), 1.f);
            const float pv = ws_pool[tid] / cnt;
            s_pooled[tid]   = pv;
            pooled_out[tid] = pv;
        }
        __syncthreads();
        if (tid < B){
            float acc = ib[0];
#pragma unroll
            for (int i = 0; i < 32; ++i) acc = fmaf(s_pooled[tid * 32 + i], iw[i], acc);
            iou_out[tid] = acc;
        }
    }

    const int q4 = tid & 3;                    // channel octet 0..3
    float sc[8], bp[8], wv0[8], wv1[8], wv2[8];
#pragma unroll
    for (int j = 0; j < 8; ++j){
        const int ch = q4 * 8 + j;
        sc[j]  = s_sc[ch];
        bp[j]  = s_bp[ch];
        wv0[j] = w2[ch * 3 + 0];
        wv1[j] = w2[ch * 3 + 1];
        wv2[j] = w2[ch * 3 + 2];
    }
    const float b2v = (q4 == 0) ? b2[0] : ((q4 == 1) ? b2[1] : b2[2]);

    const int stride = gridDim.x * (TPB / 4);
    for (int row = blockIdx.x * (TPB / 4) + (tid >> 2); row < N; row += stride){
        const short8 hv = *(const short8*)(h_in + (size_t)row * 32 + q4 * 8);
        float d0 = 0.f, d1 = 0.f, d2 = 0.f;
#pragma unroll
        for (int j = 0; j < 8; ++j){
            const float x = fmaxf(fmaf(h2f((unsigned short)hv[j]), sc[j], bp[j]), 0.f);
            d0 = fmaf(x, wv0[j], d0);
            d1 = fmaf(x, wv1[j], d1);
            d2 = fmaf(x, wv2[j], d2);
        }
        d0 += __shfl_xor(d0, 1, 64); d0 += __shfl_xor(d0, 2, 64);
        d1 += __shfl_xor(d1, 1, 64); d1 += __shfl_xor(d1, 2, 64);
        d2 += __shfl_xor(d2, 1, 64); d2 += __shfl_xor(d2, 2, 64);
        if (q4 < 3){
            const float val = (q4 == 0) ? d0 : ((q4 == 1) ? d1 : d2);
            pt_out[(size_t)row * 3 + q4] = val + b2v;
        }
    }
}

extern "C" void kernel_launch(void* const* d_in, const int* in_sizes, int n_in,
                              void* d_out, int out_size, void* d_ws, size_t ws_size,
                              hipStream_t stream) {
    const float* feats = (const float*)d_in[0];
    const int*   bidx  = (const int*)d_in[1];
    const float* w1    = (const float*)d_in[2];
    const float* b1    = (const float*)d_in[3];
    const float* gamma = (const float*)d_in[4];
    const float* beta  = (const float*)d_in[5];
    const float* w2    = (const float*)d_in[6];
    const float* b2    = (const float*)d_in[7];
    const float* mw1   = (const float*)d_in[8];
    const float* mb1   = (const float*)d_in[9];
    const float* mw2   = (const float*)d_in[10];
    const float* mb2   = (const float*)d_in[11];
    const float* iw    = (const float*)d_in[12];
    const float* ib    = (const float*)d_in[13];

    const int N = in_sizes[0] / 32;
    const int B = (out_size - 4 * N) / 33;   // out = 3N + N + 32B + B

    float* out    = (float*)d_out;
    float* pt     = out;                       // [N,3]
    float* mask   = out + (size_t)3 * N;       // [N,1]
    float* pooled = out + (size_t)4 * N;       // [B,32]
    float* iou    = pooled + (size_t)B * 32;   // [B,1]

    float* ws      = (float*)d_ws;
    float* ws_sum  = ws;                        // 32
    float* ws_sq   = ws + 32;                   // 32
    float* ws_pool = ws + 64;                   // B*32
    int*   ws_lb   = (int*)(ws + 64 + (size_t)B * 32);          // B+1 ints
    unsigned short* ws_h = (unsigned short*)(ws + 384);         // N*32 f16 (128 MB)

    (void)hipMemsetAsync(ws, 0, (size_t)(64 + B * 32) * sizeof(float), stream);

    lb_kernel<<<1, 64, 0, stream>>>(bidx, ws_lb, N, B);
    pass1_kernel<<<GRID1, TPB, 0, stream>>>(feats, ws_lb, w1, b1, mw1, mb1, mw2, mb2,
                                            mask, ws_h, ws_sum, ws_sq, ws_pool, N, B);
    pass2_kernel<<<GRID2, TPB, 0, stream>>>(ws_h, ws_lb, gamma, beta, w2, b2,
                                            iw, ib, ws_sum, ws_sq, ws_pool,
                                            pt, pooled, iou, N, B);
}